// Round 17
// baseline (272.282 us; speedup 1.0000x reference)
//
#include <hip/hip_runtime.h>
#include <hip/hip_bf16.h>

typedef __hip_bfloat16 bf16;
typedef short s8v __attribute__((ext_vector_type(8)));   // 8 bf16 = 4 VGPR MFMA frag
typedef float f4v __attribute__((ext_vector_type(4)));   // 4 fp32 MFMA acc

#define DEVI __device__ __forceinline__

DEVI float cvt(float x){ return x; }
DEVI float cvt(bf16 x){ return __bfloat162float(x); }

DEVI void stg(float* p, float v){ *p = v; }
DEVI void stg(bf16* p, float v){ *p = __float2bfloat16(v); }

DEVI float gelu_exact(float x){
  return 0.5f*x*(1.0f + erff(x*0.70710678118654752440f));
}

// problem constants
constexpr int B_ = 2, C_ = 128, H_ = 56, W_ = 56, N_ = 3136, NH_ = 4, D_ = 32, HF_ = 341;
constexpr int ROWS_ = B_*N_;             // 6272
constexpr int KF2 = 352;                 // fc2 K padded 341 -> 352 (11*32)
constexpr int GQ_ = NH_*B_*N_;           // 25088 (bh*N + n)
constexpr int FW = 512;                  // fused qkv+sr width (q 0..128 | kv 128..384 | sr 384..512)
constexpr int KSP = 4;                   // attention key splits

// ---------------- LayerNorm (one wave per row of 128 channels) ----------------
template<typename TX, typename TY, bool PLANES>
__global__ __launch_bounds__(256)
void ln_kernel(const TX* __restrict__ x, long xstr, const float* __restrict__ w,
               const float* __restrict__ bia, TY* __restrict__ y)
{
  int gid = blockIdx.x*4 + (threadIdx.x>>6);      // row over B*N
  int lane = threadIdx.x & 63;
  int b = gid / N_, n = gid % N_;
  float v0, v1;
  if (PLANES){
    v0 = cvt(x[((long)b*C_ + lane     )*N_ + n]);
    v1 = cvt(x[((long)b*C_ + lane + 64)*N_ + n]);
  } else {
    v0 = cvt(x[(long)gid*xstr + lane     ]);
    v1 = cvt(x[(long)gid*xstr + lane + 64]);
  }
  float s = v0+v1, ss = v0*v0 + v1*v1;
  #pragma unroll
  for (int o=32;o>0;o>>=1){ s += __shfl_xor(s,o); ss += __shfl_xor(ss,o); }
  float mu  = s*(1.0f/128.0f);
  float var = fmaxf(ss*(1.0f/128.0f) - mu*mu, 0.f);
  float inv = rsqrtf(var + 1e-5f);
  stg(&y[(long)gid*C_ + lane     ], (v0-mu)*inv*w[lane     ] + bia[lane     ]);
  stg(&y[(long)gid*C_ + lane + 64], (v1-mu)*inv*w[lane + 64] + bia[lane + 64]);
}

// ---------------- weight fp32 -> bf16 conversion + combined qkvsr bias ----------------
__global__ __launch_bounds__(256)
void convw_kernel(const float* __restrict__ q_w, const float* __restrict__ kv_w,
                  const float* __restrict__ sr_w, const float* __restrict__ proj_w,
                  const float* __restrict__ fc1_w, const float* __restrict__ fc2_w,
                  const float* __restrict__ q_b, const float* __restrict__ kv_b,
                  const float* __restrict__ sr_b,
                  bf16* __restrict__ out, float* __restrict__ bias_out)
{
  int t = blockIdx.x*256 + threadIdx.x;
  if (t >= 214272){
    int i = t - 214272;
    if (i < 512){
      float bv = (i < 128) ? q_b[i] : (i < 384) ? kv_b[i-128] : sr_b[i-384];
      bias_out[i] = bv;
    }
    return;
  }
  float v;
  if      (t <  16384) v = q_w[t];
  else if (t <  49152) v = kv_w[t-16384];
  else if (t <  65536) v = sr_w[t-49152];
  else if (t <  81920) v = proj_w[t-65536];
  else if (t < 169216) v = fc1_w[t-81920];
  else {
    int i = t - 169216; int m = i / KF2, kp = i % KF2;
    v = (kp < HF_) ? fc2_w[m*HF_ + kp] : 0.f;
  }
  out[t] = __float2bfloat16(v);
}

// ---------------- LDS-free MFMA GEMM (batched via blockIdx.z strides) ----------------
// MODE: 1=+bias[n]; 2=+bias[n]+gelu; 3=+bias[m]; 4=+bias[n]+res fp32; 5=+bias[m]+res fp32;
//       6=+bias[n], gelu iff n>=384 (fused qkv|sr epilogue)
template<int KT, int MODE, typename TC>
__global__ __launch_bounds__(256)
void gemm_mfma(const bf16* __restrict__ A, const bf16* __restrict__ B,
               const float* __restrict__ bias, const float* __restrict__ res,
               TC* __restrict__ Cm, int M, int Nn,
               long sA, long sB, long sC, long sR)
{
  A  += (long)blockIdx.z * sA;
  B  += (long)blockIdx.z * sB;
  Cm += (long)blockIdx.z * sC;
  if (res) res += (long)blockIdx.z * sR;
  int lane = threadIdx.x & 63, w = threadIdx.x >> 6;
  int m = lane & 15, quad = lane >> 4;
  int n0 = blockIdx.x*64, m0 = blockIdx.y*64;
  int arow = m0 + w*16 + m;
  if (arow >= M) arow = M-1;                    // clamp loads; stores guarded
  const bf16* ap = A + (long)arow*KT + quad*8;
  const bf16* bp = B + (long)(n0 + m)*KT + quad*8;
  f4v acc[4];
  #pragma unroll
  for (int s=0;s<4;s++) acc[s] = (f4v){0.f,0.f,0.f,0.f};
  #pragma unroll
  for (int k0 = 0; k0 < KT; k0 += 32){
    s8v af = *(const s8v*)(ap + k0);
    #pragma unroll
    for (int s=0;s<4;s++){
      s8v bf = *(const s8v*)(bp + (long)s*16*KT + k0);
      acc[s] = __builtin_amdgcn_mfma_f32_16x16x32_bf16(af, bf, acc[s], 0, 0, 0);
    }
  }
  #pragma unroll
  for (int s=0;s<4;s++){
    int gn = n0 + s*16 + m;
    #pragma unroll
    for (int r=0;r<4;r++){
      int gm = m0 + w*16 + quad*4 + r;
      if (gm >= M) continue;
      float v = acc[s][r];
      if (MODE==1 || MODE==2 || MODE==4 || MODE==6) v += bias[gn];
      else                                          v += bias[gm];
      if (MODE==2) v = gelu_exact(v);
      if (MODE==6 && gn >= 384) v = gelu_exact(v);
      if (MODE==4 || MODE==5) v += res[(long)gm*Nn + gn];
      stg(&Cm[(long)gm*Nn + gn], v);
    }
  }
}

// ---------------- q post-process: l2n + embed + temperature -> qs ROWS ----------------
__global__ __launch_bounds__(256)
void post_q_kernel(const bf16* __restrict__ fused, const float* __restrict__ qe,
                   const float* __restrict__ temp, bf16* __restrict__ qs)
{
  int t = blockIdx.x*256 + threadIdx.x;        // (b*4+h)*N + n
  int n = t % N_; int bh = t / N_; int h = bh & 3; int b = bh >> 2;
  float sp = log1pf(expf(temp[h]));
  const bf16* qr = fused + ((long)(b*N_ + n))*FW + h*D_;
  float v[32]; float ss = 0.f;
  #pragma unroll
  for (int d=0;d<32;d++){ v[d] = cvt(qr[d]); ss = fmaf(v[d], v[d], ss); }
  float inv = 1.f/fmaxf(sqrtf(ss), 1e-12f);
  bf16* qo = qs + ((long)bh*N_ + n)*D_;
  #pragma unroll
  for (int d=0;d<32;d++)
    stg(&qo[d], (v[d]*inv + qe[h*D_+d])*sp);
}

// ---------------- pooled kv post-process ----------------
__global__ __launch_bounds__(256)
void post_kvp_kernel(const bf16* __restrict__ kvp_raw,
                     bf16* __restrict__ kp, bf16* __restrict__ vp)
{
  int t = blockIdx.x*256 + threadIdx.x;        // bh*N + n
  int n = t % N_; int bh = t / N_; int h = bh & 3; int b = bh >> 2;
  const bf16* kr = kvp_raw + ((long)(b*N_ + n))*(2*C_) + h*D_;
  float v[32]; float ss = 0.f;
  #pragma unroll
  for (int d=0;d<32;d++){ v[d] = cvt(kr[d]); ss = fmaf(v[d], v[d], ss); }
  float inv = 1.f/fmaxf(sqrtf(ss), 1e-12f);
  bf16* ko = kp + ((long)bh*N_ + n)*D_;
  #pragma unroll
  for (int d=0;d<32;d++) stg(&ko[d], v[d]*inv);
  #pragma unroll
  for (int d=0;d<32;d++) vp[((long)bh*D_ + d)*N_ + n] = kr[C_ + d];
}

// ---------------- MFMA pool-attention PARTIAL (4 q-tiles/wave, 4-way key split) -----
// grid (13, 8, 4); block 256 = 4 waves. Wave w owns q-tiles base+{0,64,128,192},
// base = bx*256 + w*16 (tail tiles guarded). Per 64-key tile the 8 K/V fragment
// loads feed 32 MFMAs (4 independent QK->exp->LDS->PV chains share them).
// Key split z: tiles [z*768, z<3 ? +768 : N). No __syncthreads (wave-private LDS).
__global__ __launch_bounds__(256)
void attn_part_kernel(const bf16* __restrict__ qs_, const bf16* __restrict__ kp_,
                      const bf16* __restrict__ vp_,
                      bf16* __restrict__ Op, float* __restrict__ Lp)
{
  int bh = blockIdx.y;
  int z  = blockIdx.z;
  int lane = threadIdx.x & 63;
  int w    = threadIdx.x >> 6;
  int m    = lane & 15, quad = lane >> 4;
  int base = blockIdx.x*256 + w*16;
  __shared__ float sm[4][2304];                // per wave: 4x P(16x72 bf16)=9216B; Olds reuses
  bf16*  Pl   = (bf16*)sm[w];
  float* Olds = sm[w];

  s8v af[4]; bool hasQ[4];
  #pragma unroll
  for (int ch=0; ch<4; ch++){
    int qq = base + ch*64;
    hasQ[ch] = (qq < N_);
    af[ch] = *(const s8v*)(qs_ + ((long)bh*N_ + (hasQ[ch] ? qq : base) + m)*D_ + quad*8);
  }
  const bf16* kpb = kp_ + (long)bh*N_*D_;
  const bf16* vpb = vp_ + (long)bh*D_*N_;
  f4v o0[4], o1[4];
  float l[4][4];
  #pragma unroll
  for (int ch=0; ch<4; ch++){
    o0[ch] = (f4v){0.f,0.f,0.f,0.f}; o1[ch] = (f4v){0.f,0.f,0.f,0.f};
    #pragma unroll
    for (int r=0;r<4;r++) l[ch][r] = 0.f;
  }

  int tlo = z*768, thi = (z==3) ? N_ : tlo + 768;
  for (int t0 = tlo; t0 < thi; t0 += 64){
    s8v kf[4], vf[4];
    #pragma unroll
    for (int s=0;s<4;s++)
      kf[s] = *(const s8v*)(kpb + (long)(t0 + s*16 + m)*D_ + quad*8);
    vf[0] = *(const s8v*)(vpb + (long)(m     )*N_ + t0      + quad*8);
    vf[1] = *(const s8v*)(vpb + (long)(16 + m)*N_ + t0      + quad*8);
    vf[2] = *(const s8v*)(vpb + (long)(m     )*N_ + t0 + 32 + quad*8);
    vf[3] = *(const s8v*)(vpb + (long)(16 + m)*N_ + t0 + 32 + quad*8);
    // 4 independent QK chains sharing kf
    #pragma unroll
    for (int s = 0; s < 4; s++){
      #pragma unroll
      for (int ch=0; ch<4; ch++){
        f4v c = {0.f,0.f,0.f,0.f};
        c = __builtin_amdgcn_mfma_f32_16x16x32_bf16(af[ch], kf[s], c, 0, 0, 0);
        #pragma unroll
        for (int r=0;r<4;r++){
          float e = __expf(c[r] - 8.f);        // D: row=quad*4+r (query), col=m (key)
          l[ch][r] += e;
          Pl[ch*1152 + (quad*4+r)*72 + s*16 + m] = __float2bfloat16(e);
        }
      }
    }
    // PV for all chains sharing vf
    #pragma unroll
    for (int c2=0;c2<2;c2++){
      #pragma unroll
      for (int ch=0; ch<4; ch++){
        s8v pa = *(const s8v*)(Pl + ch*1152 + m*72 + c2*32 + quad*8);
        o0[ch] = __builtin_amdgcn_mfma_f32_16x16x32_bf16(pa, vf[c2*2  ], o0[ch], 0, 0, 0);
        o1[ch] = __builtin_amdgcn_mfma_f32_16x16x32_bf16(pa, vf[c2*2+1], o1[ch], 0, 0, 0);
      }
    }
  }
  // merge + store per chain (wave-private, sequential reuse of Olds)
  #pragma unroll
  for (int ch=0; ch<4; ch++){
    if (!hasQ[ch]) continue;
    float lr[4] = {l[ch][0], l[ch][1], l[ch][2], l[ch][3]};
    #pragma unroll
    for (int off=1; off<16; off<<=1)
      #pragma unroll
      for (int r=0;r<4;r++) lr[r] += __shfl_xor(lr[r], off);
    #pragma unroll
    for (int r=0;r<4;r++){
      Olds[(quad*4+r)*36 + m     ] = o0[ch][r];
      Olds[(quad*4+r)*36 + 16 + m] = o1[ch][r];
    }
    if (m == 0){
      #pragma unroll
      for (int r=0;r<4;r++) Olds[576 + quad*4 + r] = lr[r];
    }
    long gq = (long)bh*N_ + base + ch*64 + m;
    f4v ov0 = *(const f4v*)(Olds + m*36 + quad*8);
    f4v ov1 = *(const f4v*)(Olds + m*36 + quad*8 + 4);
    bf16 o8[8];
    #pragma unroll
    for (int j=0;j<4;j++){ o8[j] = __float2bfloat16(ov0[j]); o8[4+j] = __float2bfloat16(ov1[j]); }
    *(s8v*)(Op + ((long)z*GQ_ + gq)*32 + quad*8) = *(const s8v*)o8;
    if (quad == 0) Lp[(long)z*GQ_ + gq] = Olds[576 + m];
  }
}

// ---------------- combine partials + local 3x3 + learnable tokens -> xo rows --------
__global__ __launch_bounds__(256)
void attn_combine_kernel(const bf16* __restrict__ Op, const float* __restrict__ Lp,
                         const bf16* __restrict__ qs_, const bf16* __restrict__ fused,
                         const float* __restrict__ qe, const float* __restrict__ temp,
                         const float* __restrict__ tokens, const float* __restrict__ tbias,
                         bf16* __restrict__ xo)
{
  int gq = blockIdx.x*256 + threadIdx.x;       // bh*N + n, 25088 total
  int n = gq % N_; int bh = gq / N_; int h = bh & 3; int b = bh >> 2;
  float L = 0.f;
  float out[32];
  #pragma unroll
  for (int d=0;d<32;d++) out[d] = 0.f;
  #pragma unroll
  for (int z=0; z<KSP; z++){
    L += Lp[(long)z*GQ_ + gq];
    const bf16* oz = Op + ((long)z*GQ_ + gq)*32;
    #pragma unroll
    for (int d=0;d<32;d++) out[d] += cvt(oz[d]);
  }
  const bf16* qrow = qs_ + (long)gq*D_;
  float q[32];
  #pragma unroll
  for (int d=0;d<32;d++) q[d] = cvt(qrow[d]);
  int hy = n / W_, wx = n % W_;
  const bf16* kvb = fused + (long)b*N_*FW + 128 + h*D_;   // key cols
  float sl[9];
  #pragma unroll
  for (int k=0;k<9;k++){
    int di = k/3-1, dj = k%3-1;
    int yy = hy+di, xx = wx+dj;
    float s = 0.f;
    if (yy>=0 && yy<H_ && xx>=0 && xx<W_){
      long nn2 = (long)(yy*W_+xx)*FW;
      float dot = 0.f, ss = 0.f;
      #pragma unroll
      for (int d=0;d<32;d++){
        float kk = cvt(kvb[nn2 + d]);
        dot = fmaf(q[d], kk, dot);
        ss  = fmaf(kk, kk, ss);
      }
      s = dot / fmaxf(sqrtf(ss), 1e-12f);
    }
    sl[k] = s;                                  // OOB: exactly 0 (zero-padded key)
  }
  #pragma unroll
  for (int k=0;k<9;k++) L += __expf(sl[k] - 8.f);
  float invL = 1.f/L;
  #pragma unroll
  for (int d=0;d<32;d++) out[d] *= invL;
  float sp = log1pf(expf(temp[h]));
  float invsp = 1.f/sp;
  float qn[32];
  #pragma unroll
  for (int d=0;d<32;d++) qn[d] = q[d]*invsp - qe[h*D_+d];
  #pragma unroll
  for (int k=0;k<9;k++){
    float tok = 0.f;
    #pragma unroll
    for (int d=0;d<32;d++) tok = fmaf(qn[d], tokens[(h*D_+d)*9+k], tok);
    float wl = tok + tbias[h*9+k] + __expf(sl[k] - 8.f)*invL;
    int di = k/3-1, dj = k%3-1;
    int yy = hy+di, xx = wx+dj;
    if (yy>=0 && yy<H_ && xx>=0 && xx<W_){      // OOB v_l zero-padded -> contributes 0
      long nn2 = (long)(yy*W_+xx)*FW;
      #pragma unroll
      for (int d=0;d<32;d++) out[d] = fmaf(wl, cvt(kvb[nn2 + 128 + d]), out[d]);
    }
  }
  bf16* op = xo + ((long)(b*N_ + n))*C_ + h*D_;
  #pragma unroll
  for (int d=0;d<32;d++) stg(&op[d], out[d]);
}

// ---------------- depthwise 3x3 + bias + gelu, gated -> g ROWS (n, 352), both batches
__global__ __launch_bounds__(256)
void dwconv_kernel(const bf16* __restrict__ f1, const float* __restrict__ dww,
                   const float* __restrict__ dwb, bf16* __restrict__ g)
{
  int t = blockIdx.x*256 + threadIdx.x;
  if (t >= B_*N_*44) return;
  int b = t / (N_*44); int r = t - b*(N_*44);
  int n = r % N_, cg = r / N_;
  f1 += (long)b*2*HF_*N_;
  g  += (long)b*N_*KF2;
  int c0 = cg*8;
  int hy = n / W_, wx = n % W_;
  bf16 o8[8];
  #pragma unroll
  for (int j=0;j<8;j++){
    int c = c0 + j;
    float val = 0.f;
    if (c < HF_){
      const bf16* ap = f1 + (long)c*N_;
      float s = dwb[c];
      #pragma unroll
      for (int di=-1; di<=1; di++)
        #pragma unroll
        for (int dj=-1; dj<=1; dj++){
          int yy = hy+di, xx = wx+dj;
          if (yy>=0 && yy<H_ && xx>=0 && xx<W_)
            s = fmaf(dww[c*9 + (di+1)*3 + (dj+1)], cvt(ap[yy*W_+xx]), s);
        }
      val = gelu_exact(s) * cvt(f1[(long)(HF_+c)*N_ + n]);
    }
    o8[j] = __float2bfloat16(val);
  }
  *(s8v*)(g + (long)n*KF2 + c0) = *(const s8v*)o8;
}

// ---------------- launcher ----------------
extern "C" void kernel_launch(void* const* d_in, const int* in_sizes, int n_in,
                              void* d_out, int out_size, void* d_ws, size_t ws_size,
                              hipStream_t stream)
{
  (void)in_sizes; (void)n_in; (void)out_size; (void)ws_size;
  const float* x_in      = (const float*)d_in[0];
  const float* norm1_w   = (const float*)d_in[1];
  const float* norm1_b   = (const float*)d_in[2];
  const float* q_w       = (const float*)d_in[3];
  const float* q_b       = (const float*)d_in[4];
  const float* kv_w      = (const float*)d_in[5];
  const float* kv_b      = (const float*)d_in[6];
  const float* temp      = (const float*)d_in[7];
  const float* qe        = (const float*)d_in[8];
  const float* tokens    = (const float*)d_in[9];
  const float* tbias     = (const float*)d_in[10];
  const float* sr_w      = (const float*)d_in[11];
  const float* sr_b      = (const float*)d_in[12];
  const float* pln_w     = (const float*)d_in[13];
  const float* pln_b     = (const float*)d_in[14];
  const float* proj_w    = (const float*)d_in[15];
  const float* proj_b    = (const float*)d_in[16];
  const float* norm2_w   = (const float*)d_in[17];
  const float* norm2_b   = (const float*)d_in[18];
  const float* fc1_w     = (const float*)d_in[19];
  const float* fc1_b     = (const float*)d_in[20];
  const float* dw_w      = (const float*)d_in[21];
  const float* dw_b      = (const float*)d_in[22];
  const float* fc2_w     = (const float*)d_in[23];
  const float* fc2_b     = (const float*)d_in[24];

  // ---- workspace plan (bytes), peak ~22.5 MB (ws_size ~= 256 MiB measured) ----
  // [0, 6422528):        fused rows -> x2 fp32 [0,3211264) + y2 bf16 [3211264,4816896)
  // [4816896,13371904):  f1b both batches (2 x 682 x N bf16) -- written post-combine;
  //                      LN1 y rows live at its head [4816896,6422528) early on
  // [6422528, 8028160):  qs rows (alive through combine; overwritten later by f1b)
  // [8028160, 9633792):  xp -> k_p rows
  // [9633792, 11239424): v_p planes
  // [11239424,17661952): kvp_raw -> Opart (4 x 25088 x 32 bf16)
  // [17661952,22077440): g rows both batches (2 x N x 352 bf16)
  // [22077440,22505984): bf16 weights; [22505984,22508032): fused bias f32
  // d_out: xo bf16 [0,1605632) + Lpart f32 [1605632,2007040); overwritten by fc2.
  char* w8 = (char*)d_ws;
  bf16*  fused   = (bf16*)(w8 + 0);
  float* x2      = (float*)(w8 + 0);
  bf16*  y2      = (bf16*)(w8 + 3211264);
  bf16*  f1b     = (bf16*)(w8 + 4816896);
  bf16*  qs      = (bf16*)(w8 + 6422528);
  bf16*  xp      = (bf16*)(w8 + 8028160);
  bf16*  k_p     = (bf16*)(w8 + 8028160);
  bf16*  v_p     = (bf16*)(w8 + 9633792);
  bf16*  kvp_raw = (bf16*)(w8 + 11239424);
  bf16*  Opart   = (bf16*)(w8 + 11239424);
  bf16*  g_rows  = (bf16*)(w8 + 17661952);
  bf16*  wbase   = (bf16*)(w8 + 22077440);
  float* fbias   = (float*)(w8 + 22505984);
  bf16*  y       = f1b;                         // LN1 output rows (dead before f1b use)
  bf16*  xo      = (bf16*)d_out;
  float* Lpart   = (float*)((char*)d_out + 1605632);
  bf16*  proj_wb = wbase + 65536;
  bf16*  fc1_wb  = wbase + 81920;
  bf16*  fc2_wb  = wbase + 169216;

  // 0. weights -> bf16 (fc2 K-padded) + combined qkvsr bias
  convw_kernel<<<(214784+255)/256, 256, 0, stream>>>(
      q_w, kv_w, sr_w, proj_w, fc1_w, fc2_w, q_b, kv_b, sr_b, wbase, fbias);
  // 1. y = LN1(x)
  ln_kernel<float, bf16, true><<<ROWS_/4, 256, 0, stream>>>(x_in, 0, norm1_w, norm1_b, y);
  // 2. fused = y @ [q_w; kv_w; sr_w]^T + bias, gelu on sr cols (384..512)
  gemm_mfma<128, 6, bf16><<<dim3(8,98), 256, 0, stream>>>(
      y, wbase, fbias, nullptr, fused, ROWS_, FW, 0,0,0,0);
  // 3. qs rows
  post_q_kernel<<<98, 256, 0, stream>>>(fused, qe, temp, qs);
  // 4. xp = LN_pln(fused sr cols)
  ln_kernel<bf16, bf16, false><<<ROWS_/4, 256, 0, stream>>>(fused + 384, FW, pln_w, pln_b, xp);
  // 5. kvp_raw = xp @ kv_w^T + kv_b
  gemm_mfma<128, 1, bf16><<<dim3(4,98), 256, 0, stream>>>(
      xp, wbase + 16384, kv_b, nullptr, kvp_raw, ROWS_, 256, 0,0,0,0);
  // 6. k_p rows (overwrites xp) + v_p planes
  post_kvp_kernel<<<98, 256, 0, stream>>>(kvp_raw, k_p, v_p);
  // 7. pool-attention partials (4 q-tiles/wave, 4-way key split)
  attn_part_kernel<<<dim3(13,8,KSP), 256, 0, stream>>>(qs, k_p, v_p, Opart, Lpart);
  // 8. combine + local 3x3 + tokens -> xo (bf16 rows in d_out)
  attn_combine_kernel<<<GQ_/256, 256, 0, stream>>>(Opart, Lpart, qs, fused,
                                                   qe, temp, tokens, tbias, xo);
  // 9. x2 = x_in + (xo @ proj_w^T + proj_b)   (flat-reinterpret residual)
  gemm_mfma<128, 4, float><<<dim3(2,98), 256, 0, stream>>>(
      xo, proj_wb, proj_b, x_in, x2, ROWS_, 128, 0,0,0,0);
  // 10. y2 = LN2(x2)
  ln_kernel<float, bf16, true><<<ROWS_/4, 256, 0, stream>>>(x2, 0, norm2_w, norm2_b, y2);
  // 11. MLP, both batches per dispatch (z = batch)
  gemm_mfma<128, 3, bf16><<<dim3(49,11,B_), 256, 0, stream>>>(
      fc1_wb, y2, fc1_b, nullptr, f1b, 2*HF_, N_,
      0, (long)N_*C_, (long)2*HF_*N_, 0);
  dwconv_kernel<<<(B_*N_*44+255)/256, 256, 0, stream>>>(f1b, dw_w, dw_b, g_rows);
  gemm_mfma<KF2, 5, float><<<dim3(49,2,B_), 256, 0, stream>>>(
      fc2_wb, g_rows, fc2_b, x2, (float*)d_out, C_, N_,
      0, (long)N_*KF2, (long)C_*N_, (long)C_*N_);
}

// Round 18
// 268.995 us; speedup vs baseline: 1.0122x; 1.0122x over previous
//
#include <hip/hip_runtime.h>
#include <hip/hip_bf16.h>

typedef __hip_bfloat16 bf16;
typedef short s8v __attribute__((ext_vector_type(8)));   // 8 bf16 = 4 VGPR MFMA frag
typedef short s4v __attribute__((ext_vector_type(4)));   // 4 bf16 = 8B packed store
typedef float f4v __attribute__((ext_vector_type(4)));   // 4 fp32 MFMA acc

#define DEVI __device__ __forceinline__

DEVI float cvt(float x){ return x; }
DEVI float cvt(bf16 x){ return __bfloat162float(x); }

DEVI void stg(float* p, float v){ *p = v; }
DEVI void stg(bf16* p, float v){ *p = __float2bfloat16(v); }

DEVI float gelu_exact(float x){
  return 0.5f*x*(1.0f + erff(x*0.70710678118654752440f));
}

// problem constants
constexpr int B_ = 2, C_ = 128, H_ = 56, W_ = 56, N_ = 3136, NH_ = 4, D_ = 32, HF_ = 341;
constexpr int ROWS_ = B_*N_;             // 6272
constexpr int KF2 = 352;                 // fc2 K padded 341 -> 352 (11*32)
constexpr int GQ_ = NH_*B_*N_;           // 25088 (bh*N + n)
constexpr int FW = 512;                  // fused qkv+sr width (q 0..128 | kv 128..384 | sr 384..512)
constexpr int KSP = 8;                   // attention key splits

// ---------------- LayerNorm (one wave per row of 128 channels) ----------------
template<typename TX, typename TY, bool PLANES>
__global__ __launch_bounds__(256)
void ln_kernel(const TX* __restrict__ x, long xstr, const float* __restrict__ w,
               const float* __restrict__ bia, TY* __restrict__ y)
{
  int gid = blockIdx.x*4 + (threadIdx.x>>6);      // row over B*N
  int lane = threadIdx.x & 63;
  int b = gid / N_, n = gid % N_;
  float v0, v1;
  if (PLANES){
    v0 = cvt(x[((long)b*C_ + lane     )*N_ + n]);
    v1 = cvt(x[((long)b*C_ + lane + 64)*N_ + n]);
  } else {
    v0 = cvt(x[(long)gid*xstr + lane     ]);
    v1 = cvt(x[(long)gid*xstr + lane + 64]);
  }
  float s = v0+v1, ss = v0*v0 + v1*v1;
  #pragma unroll
  for (int o=32;o>0;o>>=1){ s += __shfl_xor(s,o); ss += __shfl_xor(ss,o); }
  float mu  = s*(1.0f/128.0f);
  float var = fmaxf(ss*(1.0f/128.0f) - mu*mu, 0.f);
  float inv = rsqrtf(var + 1e-5f);
  stg(&y[(long)gid*C_ + lane     ], (v0-mu)*inv*w[lane     ] + bia[lane     ]);
  stg(&y[(long)gid*C_ + lane + 64], (v1-mu)*inv*w[lane + 64] + bia[lane + 64]);
}

// ---------------- weight fp32 -> bf16 conversion + combined qkvsr bias ----------------
__global__ __launch_bounds__(256)
void convw_kernel(const float* __restrict__ q_w, const float* __restrict__ kv_w,
                  const float* __restrict__ sr_w, const float* __restrict__ proj_w,
                  const float* __restrict__ fc1_w, const float* __restrict__ fc2_w,
                  const float* __restrict__ q_b, const float* __restrict__ kv_b,
                  const float* __restrict__ sr_b,
                  bf16* __restrict__ out, float* __restrict__ bias_out)
{
  int t = blockIdx.x*256 + threadIdx.x;
  if (t >= 214272){
    int i = t - 214272;
    if (i < 512){
      float bv = (i < 128) ? q_b[i] : (i < 384) ? kv_b[i-128] : sr_b[i-384];
      bias_out[i] = bv;
    }
    return;
  }
  float v;
  if      (t <  16384) v = q_w[t];
  else if (t <  49152) v = kv_w[t-16384];
  else if (t <  65536) v = sr_w[t-49152];
  else if (t <  81920) v = proj_w[t-65536];
  else if (t < 169216) v = fc1_w[t-81920];
  else {
    int i = t - 169216; int m = i / KF2, kp = i % KF2;
    v = (kp < HF_) ? fc2_w[m*HF_ + kp] : 0.f;
  }
  out[t] = __float2bfloat16(v);
}

// ---------------- LDS-free MFMA GEMM (batched via blockIdx.z strides) ----------------
// MODE: 1=+bias[n]; 3=+bias[m]; 4=+bias[n]+res fp32; 5=+bias[m]+res fp32;
//  6 = fused qkv|sr: bx<2 -> l2norm q-head + qe + softplus(temp) -> qs rows (aux0);
//      bx>=2 -> bias (+gelu iff gn>=384) -> Cm (fused buffer)
//  7 = kvp: bx<2 -> l2norm k-head -> k_p rows (aux0); bx>=2 -> v_p planes (aux1)
template<int KT, int MODE, typename TC>
__global__ __launch_bounds__(256)
void gemm_mfma(const bf16* __restrict__ A, const bf16* __restrict__ B,
               const float* __restrict__ bias, const float* __restrict__ res,
               TC* __restrict__ Cm, int M, int Nn,
               long sA, long sB, long sC, long sR,
               const float* __restrict__ qe, const float* __restrict__ temp,
               bf16* __restrict__ aux0, bf16* __restrict__ aux1)
{
  A  += (long)blockIdx.z * sA;
  B  += (long)blockIdx.z * sB;
  Cm += (long)blockIdx.z * sC;
  if (res) res += (long)blockIdx.z * sR;
  int lane = threadIdx.x & 63, w = threadIdx.x >> 6;
  int m = lane & 15, quad = lane >> 4;
  int n0 = blockIdx.x*64, m0 = blockIdx.y*64;
  int arow = m0 + w*16 + m;
  if (arow >= M) arow = M-1;                    // clamp loads; stores guarded
  const bf16* ap = A + (long)arow*KT + quad*8;
  const bf16* bp = B + (long)(n0 + m)*KT + quad*8;
  f4v acc[4];
  #pragma unroll
  for (int s=0;s<4;s++) acc[s] = (f4v){0.f,0.f,0.f,0.f};
  #pragma unroll
  for (int k0 = 0; k0 < KT; k0 += 32){
    s8v af = *(const s8v*)(ap + k0);
    #pragma unroll
    for (int s=0;s<4;s++){
      s8v bf = *(const s8v*)(bp + (long)s*16*KT + k0);
      acc[s] = __builtin_amdgcn_mfma_f32_16x16x32_bf16(af, bf, acc[s], 0, 0, 0);
    }
  }
  // ---- specialized epilogues (M is an exact multiple of 64 for modes 6/7) ----
  if ((MODE==6 || MODE==7) && blockIdx.x < 2){
    // normalized section (q for mode 6, k for mode 7); head pair hA,hB
    int hA = blockIdx.x*2, hB = hA+1;
    float spA = 0.f, spB = 0.f;
    if (MODE==6){ spA = log1pf(expf(temp[hA])); spB = log1pf(expf(temp[hB])); }
    #pragma unroll
    for (int r=0;r<4;r++){
      float v4[4];
      #pragma unroll
      for (int s=0;s<4;s++) v4[s] = acc[s][r] + bias[n0 + s*16 + m];
      float ssA = v4[0]*v4[0] + v4[1]*v4[1];
      float ssB = v4[2]*v4[2] + v4[3]*v4[3];
      #pragma unroll
      for (int off=1; off<16; off<<=1){
        ssA += __shfl_xor(ssA, off);
        ssB += __shfl_xor(ssB, off);
      }
      float invA = 1.f/fmaxf(sqrtf(ssA), 1e-12f);
      float invB = 1.f/fmaxf(sqrtf(ssB), 1e-12f);
      int gm = m0 + w*16 + quad*4 + r;
      int b = gm / N_, n = gm % N_;
      #pragma unroll
      for (int s=0;s<4;s++){
        int h = (s<2) ? hA : hB;
        int d = (s&1)*16 + m;
        float v = v4[s] * ((s<2) ? invA : invB);
        if (MODE==6) v = (v + qe[h*D_ + d]) * ((s<2) ? spA : spB);
        aux0[((long)(b*NH_+h)*N_ + n)*D_ + d] = __float2bfloat16(v);
      }
    }
    return;
  }
  if (MODE==7){                                 // v section (bx 2,3) -> v_p planes
    int gm0 = m0 + w*16 + quad*4;
    int b = gm0 / N_, nb = gm0 % N_;            // 4 consecutive rows share b (tiles of 4)
    #pragma unroll
    for (int s=0;s<4;s++){
      int h = (blockIdx.x-2)*2 + (s>>1);
      int d = (s&1)*16 + m;
      bf16 p4[4];
      #pragma unroll
      for (int r=0;r<4;r++) p4[r] = __float2bfloat16(acc[s][r] + bias[n0 + s*16 + m]);
      *(s4v*)(aux1 + ((long)(b*NH_+h)*D_ + d)*N_ + nb) = *(const s4v*)p4;
    }
    return;
  }
  // ---- generic epilogue ----
  #pragma unroll
  for (int s=0;s<4;s++){
    int gn = n0 + s*16 + m;
    #pragma unroll
    for (int r=0;r<4;r++){
      int gm = m0 + w*16 + quad*4 + r;
      if (gm >= M) continue;
      float v = acc[s][r];
      if (MODE==1 || MODE==4 || MODE==6) v += bias[gn];
      else                               v += bias[gm];
      if (MODE==6 && gn >= 384) v = gelu_exact(v);
      if (MODE==4 || MODE==5) v += res[(long)gm*Nn + gn];
      stg(&Cm[(long)gm*Nn + gn], v);
    }
  }
}

// ---------------- MFMA pool-attention PARTIAL (4 q-tiles/wave, 8-way key split) -----
// grid (13, 8, 8); block 256 = 4 waves. Wave w owns q-tiles base+{0,64,128,192},
// base = bx*256 + w*16 (tail tiles guarded). Per 64-key tile the 8 K/V fragment
// loads feed 32 MFMAs (4 independent QK->exp->LDS->PV chains share them).
// Key split z: tiles [z*384, z<7 ? +384 : N). No __syncthreads (wave-private LDS).
__global__ __launch_bounds__(256)
void attn_part_kernel(const bf16* __restrict__ qs_, const bf16* __restrict__ kp_,
                      const bf16* __restrict__ vp_,
                      bf16* __restrict__ Op, float* __restrict__ Lp)
{
  int bh = blockIdx.y;
  int z  = blockIdx.z;
  int lane = threadIdx.x & 63;
  int w    = threadIdx.x >> 6;
  int m    = lane & 15, quad = lane >> 4;
  int base = blockIdx.x*256 + w*16;
  __shared__ float sm[4][2304];                // per wave: 4x P(16x72 bf16)=9216B; Olds reuses
  bf16*  Pl   = (bf16*)sm[w];
  float* Olds = sm[w];

  s8v af[4]; bool hasQ[4];
  #pragma unroll
  for (int ch=0; ch<4; ch++){
    int qq = base + ch*64;
    hasQ[ch] = (qq < N_);
    af[ch] = *(const s8v*)(qs_ + ((long)bh*N_ + (hasQ[ch] ? qq : base) + m)*D_ + quad*8);
  }
  const bf16* kpb = kp_ + (long)bh*N_*D_;
  const bf16* vpb = vp_ + (long)bh*D_*N_;
  f4v o0[4], o1[4];
  float l[4][4];
  #pragma unroll
  for (int ch=0; ch<4; ch++){
    o0[ch] = (f4v){0.f,0.f,0.f,0.f}; o1[ch] = (f4v){0.f,0.f,0.f,0.f};
    #pragma unroll
    for (int r=0;r<4;r++) l[ch][r] = 0.f;
  }

  int tlo = z*384, thi = (z==KSP-1) ? N_ : tlo + 384;
  for (int t0 = tlo; t0 < thi; t0 += 64){
    s8v kf[4], vf[4];
    #pragma unroll
    for (int s=0;s<4;s++)
      kf[s] = *(const s8v*)(kpb + (long)(t0 + s*16 + m)*D_ + quad*8);
    vf[0] = *(const s8v*)(vpb + (long)(m     )*N_ + t0      + quad*8);
    vf[1] = *(const s8v*)(vpb + (long)(16 + m)*N_ + t0      + quad*8);
    vf[2] = *(const s8v*)(vpb + (long)(m     )*N_ + t0 + 32 + quad*8);
    vf[3] = *(const s8v*)(vpb + (long)(16 + m)*N_ + t0 + 32 + quad*8);
    // 4 independent QK chains sharing kf
    #pragma unroll
    for (int s = 0; s < 4; s++){
      #pragma unroll
      for (int ch=0; ch<4; ch++){
        f4v c = {0.f,0.f,0.f,0.f};
        c = __builtin_amdgcn_mfma_f32_16x16x32_bf16(af[ch], kf[s], c, 0, 0, 0);
        #pragma unroll
        for (int r=0;r<4;r++){
          float e = __expf(c[r] - 8.f);        // D: row=quad*4+r (query), col=m (key)
          l[ch][r] += e;
          Pl[ch*1152 + (quad*4+r)*72 + s*16 + m] = __float2bfloat16(e);
        }
      }
    }
    // PV for all chains sharing vf
    #pragma unroll
    for (int c2=0;c2<2;c2++){
      #pragma unroll
      for (int ch=0; ch<4; ch++){
        s8v pa = *(const s8v*)(Pl + ch*1152 + m*72 + c2*32 + quad*8);
        o0[ch] = __builtin_amdgcn_mfma_f32_16x16x32_bf16(pa, vf[c2*2  ], o0[ch], 0, 0, 0);
        o1[ch] = __builtin_amdgcn_mfma_f32_16x16x32_bf16(pa, vf[c2*2+1], o1[ch], 0, 0, 0);
      }
    }
  }
  // merge + store per chain (wave-private, sequential reuse of Olds)
  #pragma unroll
  for (int ch=0; ch<4; ch++){
    if (!hasQ[ch]) continue;
    float lr[4] = {l[ch][0], l[ch][1], l[ch][2], l[ch][3]};
    #pragma unroll
    for (int off=1; off<16; off<<=1)
      #pragma unroll
      for (int r=0;r<4;r++) lr[r] += __shfl_xor(lr[r], off);
    #pragma unroll
    for (int r=0;r<4;r++){
      Olds[(quad*4+r)*36 + m     ] = o0[ch][r];
      Olds[(quad*4+r)*36 + 16 + m] = o1[ch][r];
    }
    if (m == 0){
      #pragma unroll
      for (int r=0;r<4;r++) Olds[576 + quad*4 + r] = lr[r];
    }
    long gq = (long)bh*N_ + base + ch*64 + m;
    f4v ov0 = *(const f4v*)(Olds + m*36 + quad*8);
    f4v ov1 = *(const f4v*)(Olds + m*36 + quad*8 + 4);
    bf16 o8[8];
    #pragma unroll
    for (int j=0;j<4;j++){ o8[j] = __float2bfloat16(ov0[j]); o8[4+j] = __float2bfloat16(ov1[j]); }
    *(s8v*)(Op + ((long)z*GQ_ + gq)*32 + quad*8) = *(const s8v*)o8;
    if (quad == 0) Lp[(long)z*GQ_ + gq] = Olds[576 + m];
  }
}

// ---------------- combine partials + local 3x3 + learnable tokens -> xo rows --------
__global__ __launch_bounds__(256)
void attn_combine_kernel(const bf16* __restrict__ Op, const float* __restrict__ Lp,
                         const bf16* __restrict__ qs_, const bf16* __restrict__ fused,
                         const float* __restrict__ qe, const float* __restrict__ temp,
                         const float* __restrict__ tokens, const float* __restrict__ tbias,
                         bf16* __restrict__ xo)
{
  int gq = blockIdx.x*256 + threadIdx.x;       // bh*N + n, 25088 total
  int n = gq % N_; int bh = gq / N_; int h = bh & 3; int b = bh >> 2;
  float L = 0.f;
  float out[32];
  #pragma unroll
  for (int d=0;d<32;d++) out[d] = 0.f;
  #pragma unroll
  for (int z=0; z<KSP; z++){
    L += Lp[(long)z*GQ_ + gq];
    const bf16* oz = Op + ((long)z*GQ_ + gq)*32;
    #pragma unroll
    for (int d=0;d<32;d++) out[d] += cvt(oz[d]);
  }
  const bf16* qrow = qs_ + (long)gq*D_;
  float q[32];
  #pragma unroll
  for (int d=0;d<32;d++) q[d] = cvt(qrow[d]);
  int hy = n / W_, wx = n % W_;
  const bf16* kvb = fused + (long)b*N_*FW + 128 + h*D_;   // key cols
  float sl[9];
  #pragma unroll
  for (int k=0;k<9;k++){
    int di = k/3-1, dj = k%3-1;
    int yy = hy+di, xx = wx+dj;
    float s = 0.f;
    if (yy>=0 && yy<H_ && xx>=0 && xx<W_){
      long nn2 = (long)(yy*W_+xx)*FW;
      float dot = 0.f, ss = 0.f;
      #pragma unroll
      for (int d=0;d<32;d++){
        float kk = cvt(kvb[nn2 + d]);
        dot = fmaf(q[d], kk, dot);
        ss  = fmaf(kk, kk, ss);
      }
      s = dot / fmaxf(sqrtf(ss), 1e-12f);
    }
    sl[k] = s;                                  // OOB: exactly 0 (zero-padded key)
  }
  #pragma unroll
  for (int k=0;k<9;k++) L += __expf(sl[k] - 8.f);
  float invL = 1.f/L;
  #pragma unroll
  for (int d=0;d<32;d++) out[d] *= invL;
  float sp = log1pf(expf(temp[h]));
  float invsp = 1.f/sp;
  float qn[32];
  #pragma unroll
  for (int d=0;d<32;d++) qn[d] = q[d]*invsp - qe[h*D_+d];
  #pragma unroll
  for (int k=0;k<9;k++){
    float tok = 0.f;
    #pragma unroll
    for (int d=0;d<32;d++) tok = fmaf(qn[d], tokens[(h*D_+d)*9+k], tok);
    float wl = tok + tbias[h*9+k] + __expf(sl[k] - 8.f)*invL;
    int di = k/3-1, dj = k%3-1;
    int yy = hy+di, xx = wx+dj;
    if (yy>=0 && yy<H_ && xx>=0 && xx<W_){      // OOB v_l zero-padded -> contributes 0
      long nn2 = (long)(yy*W_+xx)*FW;
      #pragma unroll
      for (int d=0;d<32;d++) out[d] = fmaf(wl, cvt(kvb[nn2 + 128 + d]), out[d]);
    }
  }
  bf16* op = xo + ((long)(b*N_ + n))*C_ + h*D_;
  #pragma unroll
  for (int d=0;d<32;d++) stg(&op[d], out[d]);
}

// ---------------- depthwise 3x3 + bias + gelu, gated -> g ROWS (n, 352), both batches
__global__ __launch_bounds__(256)
void dwconv_kernel(const bf16* __restrict__ f1, const float* __restrict__ dww,
                   const float* __restrict__ dwb, bf16* __restrict__ g)
{
  int t = blockIdx.x*256 + threadIdx.x;
  if (t >= B_*N_*44) return;
  int b = t / (N_*44); int r = t - b*(N_*44);
  int n = r % N_, cg = r / N_;
  f1 += (long)b*2*HF_*N_;
  g  += (long)b*N_*KF2;
  int c0 = cg*8;
  int hy = n / W_, wx = n % W_;
  bf16 o8[8];
  #pragma unroll
  for (int j=0;j<8;j++){
    int c = c0 + j;
    float val = 0.f;
    if (c < HF_){
      const bf16* ap = f1 + (long)c*N_;
      float s = dwb[c];
      #pragma unroll
      for (int di=-1; di<=1; di++)
        #pragma unroll
        for (int dj=-1; dj<=1; dj++){
          int yy = hy+di, xx = wx+dj;
          if (yy>=0 && yy<H_ && xx>=0 && xx<W_)
            s = fmaf(dww[c*9 + (di+1)*3 + (dj+1)], cvt(ap[yy*W_+xx]), s);
        }
      val = gelu_exact(s) * cvt(f1[(long)(HF_+c)*N_ + n]);
    }
    o8[j] = __float2bfloat16(val);
  }
  *(s8v*)(g + (long)n*KF2 + c0) = *(const s8v*)o8;
}

// ---------------- launcher ----------------
extern "C" void kernel_launch(void* const* d_in, const int* in_sizes, int n_in,
                              void* d_out, int out_size, void* d_ws, size_t ws_size,
                              hipStream_t stream)
{
  (void)in_sizes; (void)n_in; (void)out_size; (void)ws_size;
  const float* x_in      = (const float*)d_in[0];
  const float* norm1_w   = (const float*)d_in[1];
  const float* norm1_b   = (const float*)d_in[2];
  const float* q_w       = (const float*)d_in[3];
  const float* q_b       = (const float*)d_in[4];
  const float* kv_w      = (const float*)d_in[5];
  const float* kv_b      = (const float*)d_in[6];
  const float* temp      = (const float*)d_in[7];
  const float* qe        = (const float*)d_in[8];
  const float* tokens    = (const float*)d_in[9];
  const float* tbias     = (const float*)d_in[10];
  const float* sr_w      = (const float*)d_in[11];
  const float* sr_b      = (const float*)d_in[12];
  const float* pln_w     = (const float*)d_in[13];
  const float* pln_b     = (const float*)d_in[14];
  const float* proj_w    = (const float*)d_in[15];
  const float* proj_b    = (const float*)d_in[16];
  const float* norm2_w   = (const float*)d_in[17];
  const float* norm2_b   = (const float*)d_in[18];
  const float* fc1_w     = (const float*)d_in[19];
  const float* fc1_b     = (const float*)d_in[20];
  const float* dw_w      = (const float*)d_in[21];
  const float* dw_b      = (const float*)d_in[22];
  const float* fc2_w     = (const float*)d_in[23];
  const float* fc2_b     = (const float*)d_in[24];

  // ---- workspace plan (bytes), peak ~29.3 MB (ws_size ~= 256 MiB measured) ----
  // [0, 6422528):         fused rows -> x2 fp32 [0,3211264) + y2 bf16 [3211264,4816896)
  // [4816896,13371904):   f1b both batches (written at MLP; LN1 y rows at head early)
  // [6422528, 8028160):   qs rows (alive through combine; later overwritten by f1b)
  // [8028160, 9633792):   xp rows
  // [9633792, 11239424):  k_p rows
  // [11239424,13045056):  v_p planes
  // [13045056,25890112):  Opart (8 x 25088 x 32 bf16) -- dead before f1b tail written
  // [25890112,30305600):  g rows both batches
  // [30305600,30734144):  bf16 weights; [30734144,30736192): fused bias f32
  // d_out: xo bf16 [0,1605632) + Lpart f32 [1605632,2408448); overwritten by fc2.
  char* w8 = (char*)d_ws;
  bf16*  fused   = (bf16*)(w8 + 0);
  float* x2      = (float*)(w8 + 0);
  bf16*  y2      = (bf16*)(w8 + 3211264);
  bf16*  f1b     = (bf16*)(w8 + 4816896);
  bf16*  qs      = (bf16*)(w8 + 6422528);
  bf16*  xp      = (bf16*)(w8 + 8028160);
  bf16*  k_p     = (bf16*)(w8 + 9633792);
  bf16*  v_p     = (bf16*)(w8 + 11239424);
  bf16*  Opart   = (bf16*)(w8 + 13045056);
  bf16*  g_rows  = (bf16*)(w8 + 25890112);
  bf16*  wbase   = (bf16*)(w8 + 30305600);
  float* fbias   = (float*)(w8 + 30734144);
  bf16*  y       = f1b;                         // LN1 output rows (dead before f1b use)
  bf16*  xo      = (bf16*)d_out;
  float* Lpart   = (float*)((char*)d_out + 1605632);
  bf16*  proj_wb = wbase + 65536;
  bf16*  fc1_wb  = wbase + 81920;
  bf16*  fc2_wb  = wbase + 169216;

  // 0. weights -> bf16 (fc2 K-padded) + combined qkvsr bias
  convw_kernel<<<(214784+255)/256, 256, 0, stream>>>(
      q_w, kv_w, sr_w, proj_w, fc1_w, fc2_w, q_b, kv_b, sr_b, wbase, fbias);
  // 1. y = LN1(x)
  ln_kernel<float, bf16, true><<<ROWS_/4, 256, 0, stream>>>(x_in, 0, norm1_w, norm1_b, y);
  // 2. fused = y @ [q_w; kv_w; sr_w]^T + bias; q cols normalized -> qs rows (epilogue);
  //    sr cols gelu'd; kv cols plain.
  gemm_mfma<128, 6, bf16><<<dim3(8,98), 256, 0, stream>>>(
      y, wbase, fbias, nullptr, fused, ROWS_, FW, 0,0,0,0, qe, temp, qs, nullptr);
  // 3. xp = LN_pln(fused sr cols)
  ln_kernel<bf16, bf16, false><<<ROWS_/4, 256, 0, stream>>>(fused + 384, FW, pln_w, pln_b, xp);
  // 4. kvp = xp @ kv_w^T + kv_b; k cols normalized -> k_p rows; v cols -> v_p planes
  gemm_mfma<128, 7, bf16><<<dim3(4,98), 256, 0, stream>>>(
      xp, wbase + 16384, kv_b, nullptr, (bf16*)nullptr, ROWS_, 256, 0,0,0,0,
      nullptr, nullptr, k_p, v_p);
  // 5. pool-attention partials (4 q-tiles/wave, 8-way key split)
  attn_part_kernel<<<dim3(13,8,KSP), 256, 0, stream>>>(qs, k_p, v_p, Opart, Lpart);
  // 6. combine + local 3x3 + tokens -> xo (bf16 rows in d_out)
  attn_combine_kernel<<<GQ_/256, 256, 0, stream>>>(Opart, Lpart, qs, fused,
                                                   qe, temp, tokens, tbias, xo);
  // 7. x2 = x_in + (xo @ proj_w^T + proj_b)   (flat-reinterpret residual)
  gemm_mfma<128, 4, float><<<dim3(2,98), 256, 0, stream>>>(
      xo, proj_wb, proj_b, x_in, x2, ROWS_, 128, 0,0,0,0, nullptr, nullptr, nullptr, nullptr);
  // 8. y2 = LN2(x2)
  ln_kernel<float, bf16, true><<<ROWS_/4, 256, 0, stream>>>(x2, 0, norm2_w, norm2_b, y2);
  // 9. MLP, both batches per dispatch (z = batch)
  gemm_mfma<128, 3, bf16><<<dim3(49,11,B_), 256, 0, stream>>>(
      fc1_wb, y2, fc1_b, nullptr, f1b, 2*HF_, N_,
      0, (long)N_*C_, (long)2*HF_*N_, 0, nullptr, nullptr, nullptr, nullptr);
  dwconv_kernel<<<(B_*N_*44+255)/256, 256, 0, stream>>>(f1b, dw_w, dw_b, g_rows);
  gemm_mfma<KF2, 5, float><<<dim3(49,2,B_), 256, 0, stream>>>(
      fc2_wb, g_rows, fc2_b, x2, (float*)d_out, C_, N_,
      0, (long)N_*KF2, (long)C_*N_, (long)C_*N_, nullptr, nullptr, nullptr, nullptr);
}

// Round 19
// 265.463 us; speedup vs baseline: 1.0257x; 1.0133x over previous
//
#include <hip/hip_runtime.h>
#include <hip/hip_bf16.h>

typedef __hip_bfloat16 bf16;
typedef short s8v __attribute__((ext_vector_type(8)));   // 8 bf16 = 4 VGPR MFMA frag
typedef short s4v __attribute__((ext_vector_type(4)));   // 4 bf16 = 8B packed store
typedef float f4v __attribute__((ext_vector_type(4)));   // 4 fp32 MFMA acc

#define DEVI __device__ __forceinline__

DEVI float cvt(float x){ return x; }
DEVI float cvt(bf16 x){ return __bfloat162float(x); }

DEVI void stg(float* p, float v){ *p = v; }
DEVI void stg(bf16* p, float v){ *p = __float2bfloat16(v); }

DEVI float gelu_exact(float x){
  return 0.5f*x*(1.0f + erff(x*0.70710678118654752440f));
}

// problem constants
constexpr int B_ = 2, C_ = 128, H_ = 56, W_ = 56, N_ = 3136, NH_ = 4, D_ = 32, HF_ = 341;
constexpr int ROWS_ = B_*N_;             // 6272
constexpr int KF2 = 352;                 // fc2 K padded 341 -> 352 (11*32)
constexpr int GQ_ = NH_*B_*N_;           // 25088 (bh*N + n)
constexpr int FW = 512;                  // fused qkv+sr width (q 0..128 | kv 128..384 | sr 384..512)
constexpr int KSP = 4;                   // attention key splits (round-17 measured best)

// ---------------- LayerNorm (one wave per row of 128 channels) ----------------
template<typename TX, typename TY, bool PLANES>
__global__ __launch_bounds__(256)
void ln_kernel(const TX* __restrict__ x, long xstr, const float* __restrict__ w,
               const float* __restrict__ bia, TY* __restrict__ y)
{
  int gid = blockIdx.x*4 + (threadIdx.x>>6);      // row over B*N
  int lane = threadIdx.x & 63;
  int b = gid / N_, n = gid % N_;
  float v0, v1;
  if (PLANES){
    v0 = cvt(x[((long)b*C_ + lane     )*N_ + n]);
    v1 = cvt(x[((long)b*C_ + lane + 64)*N_ + n]);
  } else {
    v0 = cvt(x[(long)gid*xstr + lane     ]);
    v1 = cvt(x[(long)gid*xstr + lane + 64]);
  }
  float s = v0+v1, ss = v0*v0 + v1*v1;
  #pragma unroll
  for (int o=32;o>0;o>>=1){ s += __shfl_xor(s,o); ss += __shfl_xor(ss,o); }
  float mu  = s*(1.0f/128.0f);
  float var = fmaxf(ss*(1.0f/128.0f) - mu*mu, 0.f);
  float inv = rsqrtf(var + 1e-5f);
  stg(&y[(long)gid*C_ + lane     ], (v0-mu)*inv*w[lane     ] + bia[lane     ]);
  stg(&y[(long)gid*C_ + lane + 64], (v1-mu)*inv*w[lane + 64] + bia[lane + 64]);
}

// ---------------- weight fp32 -> bf16 conversion + combined qkvsr bias ----------------
__global__ __launch_bounds__(256)
void convw_kernel(const float* __restrict__ q_w, const float* __restrict__ kv_w,
                  const float* __restrict__ sr_w, const float* __restrict__ proj_w,
                  const float* __restrict__ fc1_w, const float* __restrict__ fc2_w,
                  const float* __restrict__ q_b, const float* __restrict__ kv_b,
                  const float* __restrict__ sr_b,
                  bf16* __restrict__ out, float* __restrict__ bias_out)
{
  int t = blockIdx.x*256 + threadIdx.x;
  if (t >= 214272){
    int i = t - 214272;
    if (i < 512){
      float bv = (i < 128) ? q_b[i] : (i < 384) ? kv_b[i-128] : sr_b[i-384];
      bias_out[i] = bv;
    }
    return;
  }
  float v;
  if      (t <  16384) v = q_w[t];
  else if (t <  49152) v = kv_w[t-16384];
  else if (t <  65536) v = sr_w[t-49152];
  else if (t <  81920) v = proj_w[t-65536];
  else if (t < 169216) v = fc1_w[t-81920];
  else {
    int i = t - 169216; int m = i / KF2, kp = i % KF2;
    v = (kp < HF_) ? fc2_w[m*HF_ + kp] : 0.f;
  }
  out[t] = __float2bfloat16(v);
}

// ---------------- LDS-free MFMA GEMM (batched via blockIdx.z strides) ----------------
// MODE: 1=+bias[n]; 3=+bias[m]; 4=+bias[n]+res fp32; 5=+bias[m]+res fp32;
//  6 = fused qkv|sr: bx<2 -> l2norm q-head + qe + softplus(temp) -> qs rows (aux0);
//      bx>=2 -> bias (+gelu iff gn>=384) -> Cm (fused buffer)
//  7 = kvp: bx<2 -> l2norm k-head -> k_p rows (aux0); bx>=2 -> v_p planes (aux1)
template<int KT, int MODE, typename TC>
__global__ __launch_bounds__(256)
void gemm_mfma(const bf16* __restrict__ A, const bf16* __restrict__ B,
               const float* __restrict__ bias, const float* __restrict__ res,
               TC* __restrict__ Cm, int M, int Nn,
               long sA, long sB, long sC, long sR,
               const float* __restrict__ qe, const float* __restrict__ temp,
               bf16* __restrict__ aux0, bf16* __restrict__ aux1)
{
  A  += (long)blockIdx.z * sA;
  B  += (long)blockIdx.z * sB;
  Cm += (long)blockIdx.z * sC;
  if (res) res += (long)blockIdx.z * sR;
  int lane = threadIdx.x & 63, w = threadIdx.x >> 6;
  int m = lane & 15, quad = lane >> 4;
  int n0 = blockIdx.x*64, m0 = blockIdx.y*64;
  int arow = m0 + w*16 + m;
  if (arow >= M) arow = M-1;                    // clamp loads; stores guarded
  const bf16* ap = A + (long)arow*KT + quad*8;
  const bf16* bp = B + (long)(n0 + m)*KT + quad*8;
  f4v acc[4];
  #pragma unroll
  for (int s=0;s<4;s++) acc[s] = (f4v){0.f,0.f,0.f,0.f};
  #pragma unroll
  for (int k0 = 0; k0 < KT; k0 += 32){
    s8v af = *(const s8v*)(ap + k0);
    #pragma unroll
    for (int s=0;s<4;s++){
      s8v bf = *(const s8v*)(bp + (long)s*16*KT + k0);
      acc[s] = __builtin_amdgcn_mfma_f32_16x16x32_bf16(af, bf, acc[s], 0, 0, 0);
    }
  }
  // ---- specialized epilogues (M is an exact multiple of 64 for modes 6/7) ----
  if ((MODE==6 || MODE==7) && blockIdx.x < 2){
    // normalized section (q for mode 6, k for mode 7); head pair hA,hB
    int hA = blockIdx.x*2, hB = hA+1;
    float spA = 0.f, spB = 0.f;
    if (MODE==6){ spA = log1pf(expf(temp[hA])); spB = log1pf(expf(temp[hB])); }
    #pragma unroll
    for (int r=0;r<4;r++){
      float v4[4];
      #pragma unroll
      for (int s=0;s<4;s++) v4[s] = acc[s][r] + bias[n0 + s*16 + m];
      float ssA = v4[0]*v4[0] + v4[1]*v4[1];
      float ssB = v4[2]*v4[2] + v4[3]*v4[3];
      #pragma unroll
      for (int off=1; off<16; off<<=1){
        ssA += __shfl_xor(ssA, off);
        ssB += __shfl_xor(ssB, off);
      }
      float invA = 1.f/fmaxf(sqrtf(ssA), 1e-12f);
      float invB = 1.f/fmaxf(sqrtf(ssB), 1e-12f);
      int gm = m0 + w*16 + quad*4 + r;
      int b = gm / N_, n = gm % N_;
      #pragma unroll
      for (int s=0;s<4;s++){
        int h = (s<2) ? hA : hB;
        int d = (s&1)*16 + m;
        float v = v4[s] * ((s<2) ? invA : invB);
        if (MODE==6) v = (v + qe[h*D_ + d]) * ((s<2) ? spA : spB);
        aux0[((long)(b*NH_+h)*N_ + n)*D_ + d] = __float2bfloat16(v);
      }
    }
    return;
  }
  if (MODE==7){                                 // v section (bx 2,3) -> v_p planes
    int gm0 = m0 + w*16 + quad*4;
    int b = gm0 / N_, nb = gm0 % N_;            // 4 consecutive rows share b (tiles of 4)
    #pragma unroll
    for (int s=0;s<4;s++){
      int h = (blockIdx.x-2)*2 + (s>>1);
      int d = (s&1)*16 + m;
      bf16 p4[4];
      #pragma unroll
      for (int r=0;r<4;r++) p4[r] = __float2bfloat16(acc[s][r] + bias[n0 + s*16 + m]);
      *(s4v*)(aux1 + ((long)(b*NH_+h)*D_ + d)*N_ + nb) = *(const s4v*)p4;
    }
    return;
  }
  // ---- generic epilogue ----
  #pragma unroll
  for (int s=0;s<4;s++){
    int gn = n0 + s*16 + m;
    #pragma unroll
    for (int r=0;r<4;r++){
      int gm = m0 + w*16 + quad*4 + r;
      if (gm >= M) continue;
      float v = acc[s][r];
      if (MODE==1 || MODE==4 || MODE==6) v += bias[gn];
      else                               v += bias[gm];
      if (MODE==6 && gn >= 384) v = gelu_exact(v);
      if (MODE==4 || MODE==5) v += res[(long)gm*Nn + gn];
      stg(&Cm[(long)gm*Nn + gn], v);
    }
  }
}

// ---------------- MFMA pool-attention PARTIAL (4 q-tiles/wave, 4-way key split) -----
// grid (13, 8, 4); block 256 = 4 waves. Wave w owns q-tiles base+{0,64,128,192},
// base = bx*256 + w*16 (tail tiles guarded). Per 64-key tile the 8 K/V fragment
// loads feed 32 MFMAs (4 independent QK->exp->LDS->PV chains share them).
// Key split z: tiles [z*768, z<3 ? +768 : N). No __syncthreads (wave-private LDS).
__global__ __launch_bounds__(256)
void attn_part_kernel(const bf16* __restrict__ qs_, const bf16* __restrict__ kp_,
                      const bf16* __restrict__ vp_,
                      bf16* __restrict__ Op, float* __restrict__ Lp)
{
  int bh = blockIdx.y;
  int z  = blockIdx.z;
  int lane = threadIdx.x & 63;
  int w    = threadIdx.x >> 6;
  int m    = lane & 15, quad = lane >> 4;
  int base = blockIdx.x*256 + w*16;
  __shared__ float sm[4][2304];                // per wave: 4x P(16x72 bf16)=9216B; Olds reuses
  bf16*  Pl   = (bf16*)sm[w];
  float* Olds = sm[w];

  s8v af[4]; bool hasQ[4];
  #pragma unroll
  for (int ch=0; ch<4; ch++){
    int qq = base + ch*64;
    hasQ[ch] = (qq < N_);
    af[ch] = *(const s8v*)(qs_ + ((long)bh*N_ + (hasQ[ch] ? qq : base) + m)*D_ + quad*8);
  }
  const bf16* kpb = kp_ + (long)bh*N_*D_;
  const bf16* vpb = vp_ + (long)bh*D_*N_;
  f4v o0[4], o1[4];
  float l[4][4];
  #pragma unroll
  for (int ch=0; ch<4; ch++){
    o0[ch] = (f4v){0.f,0.f,0.f,0.f}; o1[ch] = (f4v){0.f,0.f,0.f,0.f};
    #pragma unroll
    for (int r=0;r<4;r++) l[ch][r] = 0.f;
  }

  int tlo = z*768, thi = (z==KSP-1) ? N_ : tlo + 768;
  for (int t0 = tlo; t0 < thi; t0 += 64){
    s8v kf[4], vf[4];
    #pragma unroll
    for (int s=0;s<4;s++)
      kf[s] = *(const s8v*)(kpb + (long)(t0 + s*16 + m)*D_ + quad*8);
    vf[0] = *(const s8v*)(vpb + (long)(m     )*N_ + t0      + quad*8);
    vf[1] = *(const s8v*)(vpb + (long)(16 + m)*N_ + t0      + quad*8);
    vf[2] = *(const s8v*)(vpb + (long)(m     )*N_ + t0 + 32 + quad*8);
    vf[3] = *(const s8v*)(vpb + (long)(16 + m)*N_ + t0 + 32 + quad*8);
    // 4 independent QK chains sharing kf
    #pragma unroll
    for (int s = 0; s < 4; s++){
      #pragma unroll
      for (int ch=0; ch<4; ch++){
        f4v c = {0.f,0.f,0.f,0.f};
        c = __builtin_amdgcn_mfma_f32_16x16x32_bf16(af[ch], kf[s], c, 0, 0, 0);
        #pragma unroll
        for (int r=0;r<4;r++){
          float e = __expf(c[r] - 8.f);        // D: row=quad*4+r (query), col=m (key)
          l[ch][r] += e;
          Pl[ch*1152 + (quad*4+r)*72 + s*16 + m] = __float2bfloat16(e);
        }
      }
    }
    // PV for all chains sharing vf
    #pragma unroll
    for (int c2=0;c2<2;c2++){
      #pragma unroll
      for (int ch=0; ch<4; ch++){
        s8v pa = *(const s8v*)(Pl + ch*1152 + m*72 + c2*32 + quad*8);
        o0[ch] = __builtin_amdgcn_mfma_f32_16x16x32_bf16(pa, vf[c2*2  ], o0[ch], 0, 0, 0);
        o1[ch] = __builtin_amdgcn_mfma_f32_16x16x32_bf16(pa, vf[c2*2+1], o1[ch], 0, 0, 0);
      }
    }
  }
  // merge + store per chain (wave-private, sequential reuse of Olds)
  #pragma unroll
  for (int ch=0; ch<4; ch++){
    if (!hasQ[ch]) continue;
    float lr[4] = {l[ch][0], l[ch][1], l[ch][2], l[ch][3]};
    #pragma unroll
    for (int off=1; off<16; off<<=1)
      #pragma unroll
      for (int r=0;r<4;r++) lr[r] += __shfl_xor(lr[r], off);
    #pragma unroll
    for (int r=0;r<4;r++){
      Olds[(quad*4+r)*36 + m     ] = o0[ch][r];
      Olds[(quad*4+r)*36 + 16 + m] = o1[ch][r];
    }
    if (m == 0){
      #pragma unroll
      for (int r=0;r<4;r++) Olds[576 + quad*4 + r] = lr[r];
    }
    long gq = (long)bh*N_ + base + ch*64 + m;
    f4v ov0 = *(const f4v*)(Olds + m*36 + quad*8);
    f4v ov1 = *(const f4v*)(Olds + m*36 + quad*8 + 4);
    bf16 o8[8];
    #pragma unroll
    for (int j=0;j<4;j++){ o8[j] = __float2bfloat16(ov0[j]); o8[4+j] = __float2bfloat16(ov1[j]); }
    *(s8v*)(Op + ((long)z*GQ_ + gq)*32 + quad*8) = *(const s8v*)o8;
    if (quad == 0) Lp[(long)z*GQ_ + gq] = Olds[576 + m];
  }
}

// ---------------- combine partials + local 3x3 + learnable tokens -> xo rows --------
__global__ __launch_bounds__(256)
void attn_combine_kernel(const bf16* __restrict__ Op, const float* __restrict__ Lp,
                         const bf16* __restrict__ qs_, const bf16* __restrict__ fused,
                         const float* __restrict__ qe, const float* __restrict__ temp,
                         const float* __restrict__ tokens, const float* __restrict__ tbias,
                         bf16* __restrict__ xo)
{
  int gq = blockIdx.x*256 + threadIdx.x;       // bh*N + n, 25088 total
  int n = gq % N_; int bh = gq / N_; int h = bh & 3; int b = bh >> 2;
  float L = 0.f;
  float out[32];
  #pragma unroll
  for (int d=0;d<32;d++) out[d] = 0.f;
  #pragma unroll
  for (int z=0; z<KSP; z++){
    L += Lp[(long)z*GQ_ + gq];
    const bf16* oz = Op + ((long)z*GQ_ + gq)*32;
    #pragma unroll
    for (int d=0;d<32;d++) out[d] += cvt(oz[d]);
  }
  const bf16* qrow = qs_ + (long)gq*D_;
  float q[32];
  #pragma unroll
  for (int d=0;d<32;d++) q[d] = cvt(qrow[d]);
  int hy = n / W_, wx = n % W_;
  const bf16* kvb = fused + (long)b*N_*FW + 128 + h*D_;   // key cols
  float sl[9];
  #pragma unroll
  for (int k=0;k<9;k++){
    int di = k/3-1, dj = k%3-1;
    int yy = hy+di, xx = wx+dj;
    float s = 0.f;
    if (yy>=0 && yy<H_ && xx>=0 && xx<W_){
      long nn2 = (long)(yy*W_+xx)*FW;
      float dot = 0.f, ss = 0.f;
      #pragma unroll
      for (int d=0;d<32;d++){
        float kk = cvt(kvb[nn2 + d]);
        dot = fmaf(q[d], kk, dot);
        ss  = fmaf(kk, kk, ss);
      }
      s = dot / fmaxf(sqrtf(ss), 1e-12f);
    }
    sl[k] = s;                                  // OOB: exactly 0 (zero-padded key)
  }
  #pragma unroll
  for (int k=0;k<9;k++) L += __expf(sl[k] - 8.f);
  float invL = 1.f/L;
  #pragma unroll
  for (int d=0;d<32;d++) out[d] *= invL;
  float sp = log1pf(expf(temp[h]));
  float invsp = 1.f/sp;
  float qn[32];
  #pragma unroll
  for (int d=0;d<32;d++) qn[d] = q[d]*invsp - qe[h*D_+d];
  #pragma unroll
  for (int k=0;k<9;k++){
    float tok = 0.f;
    #pragma unroll
    for (int d=0;d<32;d++) tok = fmaf(qn[d], tokens[(h*D_+d)*9+k], tok);
    float wl = tok + tbias[h*9+k] + __expf(sl[k] - 8.f)*invL;
    int di = k/3-1, dj = k%3-1;
    int yy = hy+di, xx = wx+dj;
    if (yy>=0 && yy<H_ && xx>=0 && xx<W_){      // OOB v_l zero-padded -> contributes 0
      long nn2 = (long)(yy*W_+xx)*FW;
      #pragma unroll
      for (int d=0;d<32;d++) out[d] = fmaf(wl, cvt(kvb[nn2 + 128 + d]), out[d]);
    }
  }
  bf16* op = xo + ((long)(b*N_ + n))*C_ + h*D_;
  #pragma unroll
  for (int d=0;d<32;d++) stg(&op[d], out[d]);
}

// ---------------- depthwise 3x3 + bias + gelu, gated -> g ROWS (n, 352), both batches
__global__ __launch_bounds__(256)
void dwconv_kernel(const bf16* __restrict__ f1, const float* __restrict__ dww,
                   const float* __restrict__ dwb, bf16* __restrict__ g)
{
  int t = blockIdx.x*256 + threadIdx.x;
  if (t >= B_*N_*44) return;
  int b = t / (N_*44); int r = t - b*(N_*44);
  int n = r % N_, cg = r / N_;
  f1 += (long)b*2*HF_*N_;
  g  += (long)b*N_*KF2;
  int c0 = cg*8;
  int hy = n / W_, wx = n % W_;
  bf16 o8[8];
  #pragma unroll
  for (int j=0;j<8;j++){
    int c = c0 + j;
    float val = 0.f;
    if (c < HF_){
      const bf16* ap = f1 + (long)c*N_;
      float s = dwb[c];
      #pragma unroll
      for (int di=-1; di<=1; di++)
        #pragma unroll
        for (int dj=-1; dj<=1; dj++){
          int yy = hy+di, xx = wx+dj;
          if (yy>=0 && yy<H_ && xx>=0 && xx<W_)
            s = fmaf(dww[c*9 + (di+1)*3 + (dj+1)], cvt(ap[yy*W_+xx]), s);
        }
      val = gelu_exact(s) * cvt(f1[(long)(HF_+c)*N_ + n]);
    }
    o8[j] = __float2bfloat16(val);
  }
  *(s8v*)(g + (long)n*KF2 + c0) = *(const s8v*)o8;
}

// ---------------- launcher ----------------
extern "C" void kernel_launch(void* const* d_in, const int* in_sizes, int n_in,
                              void* d_out, int out_size, void* d_ws, size_t ws_size,
                              hipStream_t stream)
{
  (void)in_sizes; (void)n_in; (void)out_size; (void)ws_size;
  const float* x_in      = (const float*)d_in[0];
  const float* norm1_w   = (const float*)d_in[1];
  const float* norm1_b   = (const float*)d_in[2];
  const float* q_w       = (const float*)d_in[3];
  const float* q_b       = (const float*)d_in[4];
  const float* kv_w      = (const float*)d_in[5];
  const float* kv_b      = (const float*)d_in[6];
  const float* temp      = (const float*)d_in[7];
  const float* qe        = (const float*)d_in[8];
  const float* tokens    = (const float*)d_in[9];
  const float* tbias     = (const float*)d_in[10];
  const float* sr_w      = (const float*)d_in[11];
  const float* sr_b      = (const float*)d_in[12];
  const float* pln_w     = (const float*)d_in[13];
  const float* pln_b     = (const float*)d_in[14];
  const float* proj_w    = (const float*)d_in[15];
  const float* proj_b    = (const float*)d_in[16];
  const float* norm2_w   = (const float*)d_in[17];
  const float* norm2_b   = (const float*)d_in[18];
  const float* fc1_w     = (const float*)d_in[19];
  const float* fc1_b     = (const float*)d_in[20];
  const float* dw_w      = (const float*)d_in[21];
  const float* dw_b      = (const float*)d_in[22];
  const float* fc2_w     = (const float*)d_in[23];
  const float* fc2_b     = (const float*)d_in[24];

  // ---- workspace plan (bytes), peak ~23 MB (ws_size ~= 256 MiB measured) ----
  // [0, 6422528):         fused rows -> x2 fp32 [0,3211264) + y2 bf16 [3211264,4816896)
  // [4816896,13371904):   f1b both batches (written at MLP; LN1 y rows at head early)
  // [6422528, 8028160):   qs rows (alive through combine; later overwritten by f1b)
  // [8028160, 9633792):   xp rows
  // [9633792, 11239424):  k_p rows
  // [11239424,13045056):  v_p planes
  // [13045056,19467584):  Opart (4 x 25088 x 32 bf16) -- dead before f1b tail written
  // [19467584,23883072):  g rows both batches
  // [23883072,24311616):  bf16 weights; [24311616,24313664): fused bias f32
  // d_out: xo bf16 [0,1605632) + Lpart f32 [1605632,2007040); overwritten by fc2.
  char* w8 = (char*)d_ws;
  bf16*  fused   = (bf16*)(w8 + 0);
  float* x2      = (float*)(w8 + 0);
  bf16*  y2      = (bf16*)(w8 + 3211264);
  bf16*  f1b     = (bf16*)(w8 + 4816896);
  bf16*  qs      = (bf16*)(w8 + 6422528);
  bf16*  xp      = (bf16*)(w8 + 8028160);
  bf16*  k_p     = (bf16*)(w8 + 9633792);
  bf16*  v_p     = (bf16*)(w8 + 11239424);
  bf16*  Opart   = (bf16*)(w8 + 13045056);
  bf16*  g_rows  = (bf16*)(w8 + 19467584);
  bf16*  wbase   = (bf16*)(w8 + 23883072);
  float* fbias   = (float*)(w8 + 24311616);
  bf16*  y       = f1b;                         // LN1 output rows (dead before f1b use)
  bf16*  xo      = (bf16*)d_out;
  float* Lpart   = (float*)((char*)d_out + 1605632);
  bf16*  proj_wb = wbase + 65536;
  bf16*  fc1_wb  = wbase + 81920;
  bf16*  fc2_wb  = wbase + 169216;

  // 0. weights -> bf16 (fc2 K-padded) + combined qkvsr bias
  convw_kernel<<<(214784+255)/256, 256, 0, stream>>>(
      q_w, kv_w, sr_w, proj_w, fc1_w, fc2_w, q_b, kv_b, sr_b, wbase, fbias);
  // 1. y = LN1(x)
  ln_kernel<float, bf16, true><<<ROWS_/4, 256, 0, stream>>>(x_in, 0, norm1_w, norm1_b, y);
  // 2. fused = y @ [q_w; kv_w; sr_w]^T + bias; q cols normalized -> qs rows (epilogue);
  //    sr cols gelu'd; kv cols plain.
  gemm_mfma<128, 6, bf16><<<dim3(8,98), 256, 0, stream>>>(
      y, wbase, fbias, nullptr, fused, ROWS_, FW, 0,0,0,0, qe, temp, qs, nullptr);
  // 3. xp = LN_pln(fused sr cols)
  ln_kernel<bf16, bf16, false><<<ROWS_/4, 256, 0, stream>>>(fused + 384, FW, pln_w, pln_b, xp);
  // 4. kvp = xp @ kv_w^T + kv_b; k cols normalized -> k_p rows; v cols -> v_p planes
  gemm_mfma<128, 7, bf16><<<dim3(4,98), 256, 0, stream>>>(
      xp, wbase + 16384, kv_b, nullptr, (bf16*)nullptr, ROWS_, 256, 0,0,0,0,
      nullptr, nullptr, k_p, v_p);
  // 5. pool-attention partials (4 q-tiles/wave, 4-way key split)
  attn_part_kernel<<<dim3(13,8,KSP), 256, 0, stream>>>(qs, k_p, v_p, Opart, Lpart);
  // 6. combine + local 3x3 + tokens -> xo (bf16 rows in d_out)
  attn_combine_kernel<<<GQ_/256, 256, 0, stream>>>(Opart, Lpart, qs, fused,
                                                   qe, temp, tokens, tbias, xo);
  // 7. x2 = x_in + (xo @ proj_w^T + proj_b)   (flat-reinterpret residual)
  gemm_mfma<128, 4, float><<<dim3(2,98), 256, 0, stream>>>(
      xo, proj_wb, proj_b, x_in, x2, ROWS_, 128, 0,0,0,0, nullptr, nullptr, nullptr, nullptr);
  // 8. y2 = LN2(x2)
  ln_kernel<float, bf16, true><<<ROWS_/4, 256, 0, stream>>>(x2, 0, norm2_w, norm2_b, y2);
  // 9. MLP, both batches per dispatch (z = batch)
  gemm_mfma<128, 3, bf16><<<dim3(49,11,B_), 256, 0, stream>>>(
      fc1_wb, y2, fc1_b, nullptr, f1b, 2*HF_, N_,
      0, (long)N_*C_, (long)2*HF_*N_, 0, nullptr, nullptr, nullptr, nullptr);
  dwconv_kernel<<<(B_*N_*44+255)/256, 256, 0, stream>>>(f1b, dw_w, dw_b, g_rows);
  gemm_mfma<KF2, 5, float><<<dim3(49,2,B_), 256, 0, stream>>>(
      fc2_wb, g_rows, fc2_b, x2, (float*)d_out, C_, N_,
      0, (long)N_*KF2, (long)C_*N_, (long)C_*N_, nullptr, nullptr, nullptr, nullptr);
}